// Round 9
// baseline (165.270 us; speedup 1.0000x reference)
//
#include <hip/hip_runtime.h>

// Problem dims (fixed by setup_inputs)
#define NODES 8192
#define DIM   200
#define NEDGE 4096
#define DEGREE 16
#define HD    128
#define MT    8      // rows per tile in k_tail (1024 blocks)
#define ECAP  32     // per-node edge-list stride (Poisson(8); P(>32) ~ 1e-11/node)
#define CPB   512    // colsum partials (= k_xwg tile blocks)

__device__ __forceinline__ float dv_of(int cnt) {
    return 1.0f / sqrtf((float)cnt * (1.0f / 16.0f) + 1e-8f);
}

// ---- k_front: Wg rows + cnt zero (0..99) + bg (100) + text path (101..104)
__global__ void k_front(const float* __restrict__ W, const float* __restrict__ gnn_w,
                        const float* __restrict__ bias, const float* __restrict__ gnn_b,
                        const float* __restrict__ text, const float* __restrict__ text_w,
                        const float* __restrict__ text_b, const float* __restrict__ in_w,
                        const float* __restrict__ in_b, const float* __restrict__ aow,
                        const float* __restrict__ aob, const float* __restrict__ fgw,
                        const float* __restrict__ fgb, int* __restrict__ cnt,
                        float* __restrict__ Wg, float* __restrict__ bg,
                        float* __restrict__ attO, float* __restrict__ attg) {
    __shared__ float st[DIM];
    __shared__ float part[2][HD];
    __shared__ float vin[HD];
    int b = blockIdx.x, t = threadIdx.x;
    if (b < 100) {                       // Wg = W @ gnn_w, 2 rows/block; 0..31 zero cnt
        if (b < 32) cnt[b * 256 + t] = 0;            // 32*256 == NODES
        int r = 2 * b + (t >> 7);
        int c = t & 127;
        const float* vec = &W[r * DIM];
        float acc = 0.f;
        for (int k = 0; k < DIM; k++) acc += vec[k] * gnn_w[k * HD + c];
        Wg[r * HD + c] = acc;
        return;
    }
    if (b == 100) {                      // bg = bias @ gnn_w + gnn_b
        if (t < HD) {
            float acc = 0.f;
            for (int k = 0; k < DIM; k++) acc += bias[k] * gnn_w[k * HD + t];
            bg[t] = acc + gnn_b[t];
        }
        return;
    }
    // b in [101,105): text path for graph g (q/k/softmax dead: kv_len==1)
    int g = b - 101;
    int c = t & 127, h = t >> 7;
    if (t < DIM) st[t] = text[g * DIM + t];
    __syncthreads();
    {   // tp = text @ text_w + text_b   (k=200, split 100/100)
        float acc = 0.f;
        int k0 = h * 100;
        for (int k = k0; k < k0 + 100; k++) acc += st[k] * text_w[k * HD + c];
        part[h][c] = acc;
    }
    __syncthreads();
    if (t < HD) vin[t] = part[0][t] + part[1][t] + text_b[t];
    __syncthreads();
    {   // v = tp @ in_w[:, 2H:3H] + in_b[2H:3H]
        float acc = 0.f;
        int k0 = h * 64;
        for (int k = k0; k < k0 + 64; k++) acc += vin[k] * in_w[k * 3 * HD + 2 * HD + c];
        part[h][c] = acc;
    }
    __syncthreads();
    if (t < HD) vin[t] = part[0][t] + part[1][t] + in_b[2 * HD + t];
    __syncthreads();
    {   // attO = v @ aow + aob
        float acc = 0.f;
        int k0 = h * 64;
        for (int k = k0; k < k0 + 64; k++) acc += vin[k] * aow[k * HD + c];
        part[h][c] = acc;
    }
    __syncthreads();
    if (t < HD) {
        float ao = part[0][t] + part[1][t] + aob[t];
        attO[g * HD + t] = ao;
        vin[t] = ao;
    }
    __syncthreads();
    {   // attg = attO @ fgw[H:2H, :] + fgb
        float acc = 0.f;
        int k0 = h * 64;
        for (int k = k0; k < k0 + 64; k++) acc += vin[k] * fgw[(HD + k) * HD + c];
        part[h][c] = acc;
    }
    __syncthreads();
    if (t < HD) attg[g * HD + t] = part[0][t] + part[1][t] + fgb[t];
}

// ---- k_xwg (512 blocks): out2 = x@Wg (16 rows/block, 4x2 register block)
// ----   + colsum partial from staged LDS tile + edge dedupe (8 edges/block)
__global__ void k_xwg(const float* __restrict__ x, const float* __restrict__ Wg,
                      const int* __restrict__ en, float* __restrict__ out2,
                      int* __restrict__ cnt, int* __restrict__ emask,
                      int* __restrict__ elist2, float* __restrict__ cpart) {
    __shared__ float sx[16 * DIM];
    int b = blockIdx.x, t = threadIdx.x;
    // edge dedupe (set semantics) + per-node counts + incident-edge lists
    if (t < 8) {
        int e = b * 8 + t;               // 512*8 == NEDGE
        int idx[DEGREE];
#pragma unroll
        for (int i = 0; i < DEGREE; i++) idx[i] = en[e * DEGREE + i];
        int mask = 0;
#pragma unroll
        for (int i = 0; i < DEGREE; i++) {
            bool uniq = true;
            for (int j = 0; j < i; j++) uniq = uniq && (idx[j] != idx[i]);
            if (uniq) {
                mask |= (1 << i);
                int slot = atomicAdd(&cnt[idx[i]], 1);   // slot doubles as list index
                if (slot < ECAP) elist2[idx[i] * ECAP + slot] = e;
            }
        }
        emask[e] = mask;
    }
    // stage 16-row x tile
    int bm = b * 16;
    const float4* x4 = (const float4*)(x + bm * DIM);
    float4* sx4 = (float4*)sx;
    for (int i = t; i < 16 * DIM / 4; i += 256) sx4[i] = x4[i];
    __syncthreads();
    // colsum partial (free: tile already in LDS; alpha reduced in k_tE)
    if (t < DIM) {
        float s = 0.f;
#pragma unroll
        for (int r = 0; r < 16; r++) s += sx[r * DIM + t];
        cpart[b * DIM + t] = s;
    }
    // out2 tile: 4 rows x 2 cols per thread (wave-uniform rg -> LDS broadcast)
    int rg = t >> 6;                     // 0..3 -> rows rg*4..rg*4+3
    int c0 = t & 63;                     // cols c0 and c0+64
    float acc[4][2] = {{0.f,0.f},{0.f,0.f},{0.f,0.f},{0.f,0.f}};
    for (int k = 0; k < DIM; k++) {
        float w0 = Wg[k * HD + c0];
        float w1 = Wg[k * HD + c0 + 64];
#pragma unroll
        for (int i = 0; i < 4; i++) {
            float s = sx[(rg * 4 + i) * DIM + k];
            acc[i][0] += s * w0;
            acc[i][1] += s * w1;
        }
    }
#pragma unroll
    for (int i = 0; i < 4; i++) {
        out2[(bm + rg * 4 + i) * HD + c0]      = acc[i][0];
        out2[(bm + rg * 4 + i) * HD + c0 + 64] = acc[i][1];
    }
}

// ---- k_tE: blocks 0..2047 = tE (2 edges/block, pipelined unconditional gather);
// ----       block 2048 = tE zero row + alpha from cpart
__global__ void k_tE(const int* __restrict__ en, const int* __restrict__ emask,
                     const int* __restrict__ cnt, const float* __restrict__ out2,
                     float* __restrict__ tE, const float* __restrict__ cpart,
                     const float* __restrict__ gate_w, const float* __restrict__ gate_b,
                     float* __restrict__ alpha) {
    int t = threadIdx.x;
    if (blockIdx.x == NEDGE / 2) {       // zero row for k_tail's padded gather + alpha
        if (t < HD) tE[NEDGE * HD + t] = 0.f;
        __shared__ float red[256];
        float v = 0.f;
        if (t < DIM) {
            float s = 0.f;
            for (int q = 0; q < CPB; q++) s += cpart[q * DIM + t];
            v = s * gate_w[t];
        }
        red[t] = v;
        __syncthreads();
        for (int o = 128; o > 0; o >>= 1) {
            if (t < o) red[t] += red[t + o];
            __syncthreads();
        }
        if (t == 0) {
            float z = red[0] / (float)NODES + gate_b[0];
            alpha[0] = 1.0f / (1.0f + expf(-z));
        }
        return;
    }
    int e = blockIdx.x * 2 + (t >> 7);
    int c = t & 127;
    int m = emask[e];
    float De = (float)__popc(m) * (1.0f / 16.0f);
    float de = 1.0f / (De + 1e-8f);
    int nd[DEGREE];
#pragma unroll
    for (int i = 0; i < DEGREE; i++) nd[i] = en[e * DEGREE + i];
    // all loads valid (nd in [0,NODES)); issue unconditionally, mask the accumulate
    float acc = 0.f;
#pragma unroll
    for (int i = 0; i < DEGREE; i++) {
        float dvv = dv_of(cnt[nd[i]]);
        float vv  = out2[nd[i] * HD + c];
        acc += ((m >> i) & 1) ? dvv * vv : 0.f;
    }
    tE[e * HD + c] = de * acc;
}

// ---- fused tail, 8-row tiles (1024 blocks):
// pipelined edge gather -> gp -> gate -> fused -> out = fused@opw + opb
__global__ void k_tail(const float* __restrict__ out2, const float* __restrict__ tE,
                       const int* __restrict__ cnt, const int* __restrict__ elist2,
                       const float* __restrict__ alpha, const float* __restrict__ bg,
                       const float* __restrict__ fgw, const float* __restrict__ attO,
                       const float* __restrict__ attg, const float* __restrict__ opw,
                       const float* __restrict__ opb, float* __restrict__ out) {
    __shared__ float sgp[MT][HD];
    __shared__ int   sid[MT][ECAP];
    __shared__ int   scount[MT];
    int bm = blockIdx.x * MT;
    int b = bm >> 11;                    // graph id (2048 nodes/graph; tiles don't straddle)
    int t = threadIdx.x;
    // phase 0: stage per-row edge lists into LDS (32 threads per row);
    // empty slots point at the zero row tE[NEDGE] so the gather needs no mask.
    {
        int r = t >> 5, sl = t & 31;
        int n = bm + r;
        int cc = cnt[n]; cc = cc < ECAP ? cc : ECAP;
        if (sl == 0) scount[r] = cc;
        sid[r][sl] = (sl < cc) ? elist2[n * ECAP + sl] : NEDGE;
    }
    __syncthreads();
    int c = t & 127, rg = t >> 7;
    float a = alpha[0];
    float bgc = bg[c];
    // phase 1: gp rows into LDS; first 8 gather loads issue back-to-back
    // (unconditional, zero-row-padded), uniform tail loop covers cc>8.
#pragma unroll
    for (int i = 0; i < 4; i++) {
        int r = rg * 4 + i;              // wave-uniform -> cc uniform, no divergence
        int n = bm + r;
        int cc = scount[r];
        float hyp = 0.f;
#pragma unroll
        for (int j = 0; j < 8; j++) hyp += tE[sid[r][j] * HD + c];
        for (int j = 8; j < cc; j++) hyp += tE[sid[r][j] * HD + c];
        hyp *= dv_of(cnt[n]) * (1.0f / 256.0f);
        sgp[r][c] = a * out2[n * HD + c] + (1.0f - a) * hyp + bgc;
    }
    __syncthreads();
    // phase 2: gate logits (weight element reused across 4 rows)
    float ao = attO[b * HD + c];
    float ag = attg[b * HD + c];
    float acc[4] = {ag, ag, ag, ag};
    for (int j = 0; j < HD; j++) {
        float w = fgw[j * HD + c];
#pragma unroll
        for (int i = 0; i < 4; i++) acc[i] += sgp[rg * 4 + i][j] * w;
    }
    __syncthreads();
    // phase 3: fused = g*gp + (1-g)*attO, in place
#pragma unroll
    for (int i = 0; i < 4; i++) {
        int r = rg * 4 + i;
        float g = 1.0f / (1.0f + expf(-acc[i]));
        sgp[r][c] = g * sgp[r][c] + (1.0f - g) * ao;
    }
    __syncthreads();
    // phase 4: out = fused @ opw + opb (threads 0..199 own one output col)
    if (t < DIM) {
        float accO[MT];
        float ob = opb[t];
#pragma unroll
        for (int i = 0; i < MT; i++) accO[i] = ob;
        for (int j = 0; j < HD; j++) {
            float w = opw[j * DIM + t];
#pragma unroll
            for (int i = 0; i < MT; i++) accO[i] += sgp[i][j] * w;
        }
#pragma unroll
        for (int i = 0; i < MT; i++) out[(bm + i) * DIM + t] = accO[i];
    }
}

extern "C" void kernel_launch(void* const* d_in, const int* in_sizes, int n_in,
                              void* d_out, int out_size, void* d_ws, size_t ws_size,
                              hipStream_t stream) {
    const float* x      = (const float*)d_in[0];
    const float* text   = (const float*)d_in[1];
    const float* W      = (const float*)d_in[2];
    const float* bias   = (const float*)d_in[3];
    const float* gate_w = (const float*)d_in[4];
    const float* gate_b = (const float*)d_in[5];
    const float* gnn_w  = (const float*)d_in[6];
    const float* gnn_b  = (const float*)d_in[7];
    const float* text_w = (const float*)d_in[8];
    const float* text_b = (const float*)d_in[9];
    const float* in_w   = (const float*)d_in[10];
    const float* in_b   = (const float*)d_in[11];
    const float* aow    = (const float*)d_in[12];
    const float* aob    = (const float*)d_in[13];
    const float* fgw    = (const float*)d_in[14];
    const float* fgb    = (const float*)d_in[15];
    const float* opw    = (const float*)d_in[16];
    const float* opb    = (const float*)d_in[17];
    const int*   en     = (const int*)d_in[18];
    float* out = (float*)d_out;

    // Scratch layout (~8.6 MB of d_ws). Nothing needs pre-zeroing:
    // cnt zeroed in k_front; cpart/emask/elist2 fully overwritten before read;
    // tE zero-row + alpha written by k_tE block 2048.
    char* q = (char*)d_ws;
    int*   cnt    = (int*)q;   q += NODES * sizeof(int);
    float* cpart  = (float*)q; q += (size_t)CPB * DIM * sizeof(float);        // 400 KB
    float* out2   = (float*)q; q += (size_t)NODES * HD * sizeof(float);       // 4 MB
    float* tE     = (float*)q; q += (size_t)(NEDGE + 1) * HD * sizeof(float); // 2 MB + zero row
    int*   elist2 = (int*)q;   q += (size_t)NODES * ECAP * sizeof(int);       // 1 MB
    float* Wg     = (float*)q; q += DIM * HD * sizeof(float);
    float* alpha  = (float*)q; q += sizeof(float);
    float* bg     = (float*)q; q += HD * sizeof(float);
    float* attO   = (float*)q; q += 4 * HD * sizeof(float);
    float* attg   = (float*)q; q += 4 * HD * sizeof(float);
    int*   emask  = (int*)q;   q += NEDGE * sizeof(int);

    k_front<<<105, 256, 0, stream>>>(W, gnn_w, bias, gnn_b, text, text_w, text_b,
                                     in_w, in_b, aow, aob, fgw, fgb,
                                     cnt, Wg, bg, attO, attg);
    k_xwg<<<512, 256, 0, stream>>>(x, Wg, en, out2, cnt, emask, elist2, cpart);
    k_tE<<<NEDGE / 2 + 1, 256, 0, stream>>>(en, emask, cnt, out2, tE,
                                            cpart, gate_w, gate_b, alpha);
    k_tail<<<NODES / MT, 256, 0, stream>>>(out2, tE, cnt, elist2, alpha, bg, fgw,
                                           attO, attg, opw, opb, out);
}

// Round 10
// 155.895 us; speedup vs baseline: 1.0601x; 1.0601x over previous
//
#include <hip/hip_runtime.h>

// Problem dims (fixed by setup_inputs)
#define NODES 8192
#define DIM   200
#define NEDGE 4096
#define DEGREE 16
#define HD    128
#define MT    8      // rows per tile in k_tail (1024 blocks)
#define ECAP  32     // per-node edge-list stride (Poisson(8); P(>32) ~ 1e-11/node)

__device__ __forceinline__ float dv_of(int cnt) {
    return 1.0f / sqrtf((float)cnt * (1.0f / 16.0f) + 1e-8f);
}

// ---- k_front: cnt zero + colsum partials (0..255) + Wg rows (256..355)
// ----          + bg (356) + text path (357..360).  No atomics, no memset needed.
__global__ void k_front(const float* __restrict__ x, const float* __restrict__ W,
                        const float* __restrict__ gnn_w, const float* __restrict__ bias,
                        const float* __restrict__ gnn_b, const float* __restrict__ text,
                        const float* __restrict__ text_w, const float* __restrict__ text_b,
                        const float* __restrict__ in_w, const float* __restrict__ in_b,
                        const float* __restrict__ aow, const float* __restrict__ aob,
                        const float* __restrict__ fgw, const float* __restrict__ fgb,
                        float* __restrict__ cpart, int* __restrict__ cnt,
                        float* __restrict__ Wg, float* __restrict__ bg,
                        float* __restrict__ attO, float* __restrict__ attg) {
    __shared__ float st[DIM];
    __shared__ float part[2][HD];
    __shared__ float vin[HD];
    int b = blockIdx.x, t = threadIdx.x;
    if (b < 256) {                       // colsum partials (atomic-free) + zero cnt
        if (t < 32) cnt[b * 32 + t] = 0;             // 256*32 == NODES
        if (t < DIM) {
            float acc = 0.f;
            int r0 = b * 32;
            for (int r = 0; r < 32; r++) acc += x[(r0 + r) * DIM + t];
            cpart[b * DIM + t] = acc;
        }
        return;
    }
    if (b < 356) {                       // Wg = W @ gnn_w, 2 rows per block
        int r = 2 * (b - 256) + (t >> 7);
        int c = t & 127;
        const float* vec = &W[r * DIM];
        float acc = 0.f;
        for (int k = 0; k < DIM; k++) acc += vec[k] * gnn_w[k * HD + c];
        Wg[r * HD + c] = acc;
        return;
    }
    if (b == 356) {                      // bg = bias @ gnn_w + gnn_b
        if (t < HD) {
            float acc = 0.f;
            for (int k = 0; k < DIM; k++) acc += bias[k] * gnn_w[k * HD + t];
            bg[t] = acc + gnn_b[t];
        }
        return;
    }
    // b in [357,361): text path for graph g (q/k/softmax dead: kv_len==1)
    int g = b - 357;
    int c = t & 127, h = t >> 7;
    if (t < DIM) st[t] = text[g * DIM + t];
    __syncthreads();
    {   // tp = text @ text_w + text_b   (k=200, split 100/100)
        float acc = 0.f;
        int k0 = h * 100;
        for (int k = k0; k < k0 + 100; k++) acc += st[k] * text_w[k * HD + c];
        part[h][c] = acc;
    }
    __syncthreads();
    if (t < HD) vin[t] = part[0][t] + part[1][t] + text_b[t];
    __syncthreads();
    {   // v = tp @ in_w[:, 2H:3H] + in_b[2H:3H]
        float acc = 0.f;
        int k0 = h * 64;
        for (int k = k0; k < k0 + 64; k++) acc += vin[k] * in_w[k * 3 * HD + 2 * HD + c];
        part[h][c] = acc;
    }
    __syncthreads();
    if (t < HD) vin[t] = part[0][t] + part[1][t] + in_b[2 * HD + t];
    __syncthreads();
    {   // attO = v @ aow + aob
        float acc = 0.f;
        int k0 = h * 64;
        for (int k = k0; k < k0 + 64; k++) acc += vin[k] * aow[k * HD + c];
        part[h][c] = acc;
    }
    __syncthreads();
    if (t < HD) {
        float ao = part[0][t] + part[1][t] + aob[t];
        attO[g * HD + t] = ao;
        vin[t] = ao;
    }
    __syncthreads();
    {   // attg = attO @ fgw[H:2H, :] + fgb
        float acc = 0.f;
        int k0 = h * 64;
        for (int k = k0; k < k0 + 64; k++) acc += vin[k] * fgw[(HD + k) * HD + c];
        part[h][c] = acc;
    }
    __syncthreads();
    if (t < HD) attg[g * HD + t] = part[0][t] + part[1][t] + fgb[t];
}

// ---- k_xwg: blocks 0..511 = out2 = x@Wg (16 rows/block, 4x2 register block)
// ----        + edge dedupe (8 edges/block, t<8); block 512 = alpha from cpart
__global__ void k_xwg(const float* __restrict__ x, const float* __restrict__ Wg,
                      const int* __restrict__ en, float* __restrict__ out2,
                      int* __restrict__ cnt, int* __restrict__ emask,
                      int* __restrict__ elist2, const float* __restrict__ cpart,
                      const float* __restrict__ gate_w, const float* __restrict__ gate_b,
                      float* __restrict__ alpha) {
    __shared__ float sx[16 * DIM];
    int t = threadIdx.x;
    if (blockIdx.x == 512) {             // alpha = sigmoid(mean(x)@gate_w + gate_b)
        __shared__ float red[256];
        float v = 0.f;
        if (t < DIM) {
            float s = 0.f;
            for (int q = 0; q < 256; q++) s += cpart[q * DIM + t];
            v = s * gate_w[t];
        }
        red[t] = v;
        __syncthreads();
        for (int o = 128; o > 0; o >>= 1) {
            if (t < o) red[t] += red[t + o];
            __syncthreads();
        }
        if (t == 0) {
            float z = red[0] / (float)NODES + gate_b[0];
            alpha[0] = 1.0f / (1.0f + expf(-z));
        }
        return;
    }
    int b = blockIdx.x;
    // edge dedupe (set semantics) + per-node counts + incident-edge lists
    if (t < 8) {
        int e = b * 8 + t;               // 512*8 == NEDGE
        int idx[DEGREE];
#pragma unroll
        for (int i = 0; i < DEGREE; i++) idx[i] = en[e * DEGREE + i];
        int mask = 0;
#pragma unroll
        for (int i = 0; i < DEGREE; i++) {
            bool uniq = true;
            for (int j = 0; j < i; j++) uniq = uniq && (idx[j] != idx[i]);
            if (uniq) {
                mask |= (1 << i);
                int slot = atomicAdd(&cnt[idx[i]], 1);   // slot doubles as list index
                if (slot < ECAP) elist2[idx[i] * ECAP + slot] = e;
            }
        }
        emask[e] = mask;
    }
    // out2 tile: 16 rows, 4 rows x 2 cols per thread (wave-uniform rg -> LDS broadcast)
    int bm = b * 16;
    const float4* x4 = (const float4*)(x + bm * DIM);
    float4* sx4 = (float4*)sx;
    for (int i = t; i < 16 * DIM / 4; i += 256) sx4[i] = x4[i];
    __syncthreads();
    int rg = t >> 6;                     // 0..3 -> rows rg*4..rg*4+3
    int c0 = t & 63;                     // cols c0 and c0+64
    float acc[4][2] = {{0.f,0.f},{0.f,0.f},{0.f,0.f},{0.f,0.f}};
    for (int k = 0; k < DIM; k++) {
        float w0 = Wg[k * HD + c0];
        float w1 = Wg[k * HD + c0 + 64];
#pragma unroll
        for (int i = 0; i < 4; i++) {
            float s = sx[(rg * 4 + i) * DIM + k];
            acc[i][0] += s * w0;
            acc[i][1] += s * w1;
        }
    }
#pragma unroll
    for (int i = 0; i < 4; i++) {
        out2[(bm + rg * 4 + i) * HD + c0]      = acc[i][0];
        out2[(bm + rg * 4 + i) * HD + c0 + 64] = acc[i][1];
    }
}

// ---- k_tE: blocks 0..2047 = tE (2 edges/block); block 2048 zeroes tE[NEDGE] row ----
__global__ void k_tE(const int* __restrict__ en, const int* __restrict__ emask,
                     const int* __restrict__ cnt, const float* __restrict__ out2,
                     float* __restrict__ tE) {
    int t = threadIdx.x;
    if (blockIdx.x == NEDGE / 2) {       // zero row used to pad k_tail's gather
        if (t < HD) tE[NEDGE * HD + t] = 0.f;
        return;
    }
    int e = blockIdx.x * 2 + (t >> 7);
    int c = t & 127;
    int m = emask[e];
    float De = (float)__popc(m) * (1.0f / 16.0f);
    float de = 1.0f / (De + 1e-8f);
    int nd[DEGREE];
#pragma unroll
    for (int i = 0; i < DEGREE; i++) nd[i] = en[e * DEGREE + i];
    float acc = 0.f;
#pragma unroll
    for (int i = 0; i < DEGREE; i++)
        if ((m >> i) & 1) acc += dv_of(cnt[nd[i]]) * out2[nd[i] * HD + c];
    tE[e * HD + c] = de * acc;
}

// ---- fused tail, 8-row tiles (1024 blocks):
// pipelined edge gather -> gp -> gate -> fused -> out = fused@opw + opb
__global__ void k_tail(const float* __restrict__ out2, const float* __restrict__ tE,
                       const int* __restrict__ cnt, const int* __restrict__ elist2,
                       const float* __restrict__ alpha, const float* __restrict__ bg,
                       const float* __restrict__ fgw, const float* __restrict__ attO,
                       const float* __restrict__ attg, const float* __restrict__ opw,
                       const float* __restrict__ opb, float* __restrict__ out) {
    __shared__ float sgp[MT][HD];
    __shared__ int   sid[MT][ECAP];
    __shared__ int   scount[MT];
    int bm = blockIdx.x * MT;
    int b = bm >> 11;                    // graph id (2048 nodes/graph; tiles don't straddle)
    int t = threadIdx.x;
    // phase 0: stage per-row edge lists into LDS (32 threads per row);
    // empty slots point at the zero row tE[NEDGE] so the gather needs no mask.
    {
        int r = t >> 5, sl = t & 31;
        int n = bm + r;
        int cc = cnt[n]; cc = cc < ECAP ? cc : ECAP;
        if (sl == 0) scount[r] = cc;
        sid[r][sl] = (sl < cc) ? elist2[n * ECAP + sl] : NEDGE;
    }
    __syncthreads();
    int c = t & 127, rg = t >> 7;
    float a = alpha[0];
    float bgc = bg[c];
    // phase 1: gp rows into LDS; first 8 gather loads issue back-to-back
    // (unconditional, zero-row-padded), uniform tail loop covers cc>8.
#pragma unroll
    for (int i = 0; i < 4; i++) {
        int r = rg * 4 + i;              // wave-uniform -> cc uniform, no divergence
        int n = bm + r;
        int cc = scount[r];
        float hyp = 0.f;
#pragma unroll
        for (int j = 0; j < 8; j++) hyp += tE[sid[r][j] * HD + c];
        for (int j = 8; j < cc; j++) hyp += tE[sid[r][j] * HD + c];
        hyp *= dv_of(cnt[n]) * (1.0f / 256.0f);
        sgp[r][c] = a * out2[n * HD + c] + (1.0f - a) * hyp + bgc;
    }
    __syncthreads();
    // phase 2: gate logits (weight element reused across 4 rows)
    float ao = attO[b * HD + c];
    float ag = attg[b * HD + c];
    float acc[4] = {ag, ag, ag, ag};
    for (int j = 0; j < HD; j++) {
        float w = fgw[j * HD + c];
#pragma unroll
        for (int i = 0; i < 4; i++) acc[i] += sgp[rg * 4 + i][j] * w;
    }
    __syncthreads();
    // phase 3: fused = g*gp + (1-g)*attO, in place
#pragma unroll
    for (int i = 0; i < 4; i++) {
        int r = rg * 4 + i;
        float g = 1.0f / (1.0f + expf(-acc[i]));
        sgp[r][c] = g * sgp[r][c] + (1.0f - g) * ao;
    }
    __syncthreads();
    // phase 4: out = fused @ opw + opb (threads 0..199 own one output col)
    if (t < DIM) {
        float accO[MT];
        float ob = opb[t];
#pragma unroll
        for (int i = 0; i < MT; i++) accO[i] = ob;
        for (int j = 0; j < HD; j++) {
            float w = opw[j * DIM + t];
#pragma unroll
            for (int i = 0; i < MT; i++) accO[i] += sgp[i][j] * w;
        }
#pragma unroll
        for (int i = 0; i < MT; i++) out[(bm + i) * DIM + t] = accO[i];
    }
}

extern "C" void kernel_launch(void* const* d_in, const int* in_sizes, int n_in,
                              void* d_out, int out_size, void* d_ws, size_t ws_size,
                              hipStream_t stream) {
    const float* x      = (const float*)d_in[0];
    const float* text   = (const float*)d_in[1];
    const float* W      = (const float*)d_in[2];
    const float* bias   = (const float*)d_in[3];
    const float* gate_w = (const float*)d_in[4];
    const float* gate_b = (const float*)d_in[5];
    const float* gnn_w  = (const float*)d_in[6];
    const float* gnn_b  = (const float*)d_in[7];
    const float* text_w = (const float*)d_in[8];
    const float* text_b = (const float*)d_in[9];
    const float* in_w   = (const float*)d_in[10];
    const float* in_b   = (const float*)d_in[11];
    const float* aow    = (const float*)d_in[12];
    const float* aob    = (const float*)d_in[13];
    const float* fgw    = (const float*)d_in[14];
    const float* fgb    = (const float*)d_in[15];
    const float* opw    = (const float*)d_in[16];
    const float* opb    = (const float*)d_in[17];
    const int*   en     = (const int*)d_in[18];
    float* out = (float*)d_out;

    // Scratch layout (~8.2 MB of d_ws). Nothing needs pre-zeroing:
    // cnt zeroed in k_front; cpart/emask/elist2 fully overwritten before read;
    // tE zero-row written by k_tE block 2048.
    char* q = (char*)d_ws;
    int*   cnt    = (int*)q;   q += NODES * sizeof(int);
    float* cpart  = (float*)q; q += 256 * DIM * sizeof(float);
    float* out2   = (float*)q; q += (size_t)NODES * HD * sizeof(float);       // 4 MB
    float* tE     = (float*)q; q += (size_t)(NEDGE + 1) * HD * sizeof(float); // 2 MB + zero row
    int*   elist2 = (int*)q;   q += (size_t)NODES * ECAP * sizeof(int);       // 1 MB
    float* Wg     = (float*)q; q += DIM * HD * sizeof(float);
    float* alpha  = (float*)q; q += sizeof(float);
    float* bg     = (float*)q; q += HD * sizeof(float);
    float* attO   = (float*)q; q += 4 * HD * sizeof(float);
    float* attg   = (float*)q; q += 4 * HD * sizeof(float);
    int*   emask  = (int*)q;   q += NEDGE * sizeof(int);

    k_front<<<361, 256, 0, stream>>>(x, W, gnn_w, bias, gnn_b, text, text_w, text_b,
                                     in_w, in_b, aow, aob, fgw, fgb,
                                     cpart, cnt, Wg, bg, attO, attg);
    k_xwg<<<513, 256, 0, stream>>>(x, Wg, en, out2, cnt, emask, elist2,
                                   cpart, gate_w, gate_b, alpha);
    k_tE<<<NEDGE / 2 + 1, 256, 0, stream>>>(en, emask, cnt, out2, tE);
    k_tail<<<NODES / MT, 256, 0, stream>>>(out2, tE, cnt, elist2, alpha, bg, fgw,
                                           attO, attg, opw, opb, out);
}